// Round 16
// baseline (144.527 us; speedup 1.0000x reference)
//
#include <hip/hip_runtime.h>
#include <hip/hip_bf16.h>

typedef short bf16x8 __attribute__((ext_vector_type(8)));
typedef float f32x4  __attribute__((ext_vector_type(4)));
typedef unsigned int u32x4 __attribute__((ext_vector_type(4)));

#define LOG2E 1.44269504088896340736f

static __device__ __forceinline__ unsigned short f2bf(float f){
    __hip_bfloat16 h = __float2bfloat16(f);
    return __builtin_bit_cast(unsigned short, h);
}
static __device__ __forceinline__ unsigned pk_bf16(float lo, float hi){
    return (((unsigned)f2bf(hi)) << 16) | (unsigned)f2bf(lo);
}
static __device__ __forceinline__ float rcp_(float x){ return __builtin_amdgcn_rcpf(x); }
static __device__ __forceinline__ float ex2(float x){ return __builtin_amdgcn_exp2f(x); }
static __device__ __forceinline__ f32x4 mfma16(bf16x8 a, bf16x8 b, f32x4 c){
    return __builtin_amdgcn_mfma_f32_16x16x32_bf16(a, b, c, 0, 0, 0);
}
static __device__ __forceinline__ unsigned relu_pk(unsigned v){
    unsigned m = ((v >> 15) & 0x00010001u) * 0xFFFFu;
    return v & ~m;
}

__global__ void marker_kernel(float* out, int n, float v){
    int i = blockIdx.x * 256 + threadIdx.x;
    if (i < n) out[i] = v;
}

// v6b: unit-split wave pair, one pair per 128-thread block (barrier couples
// only the two waves that exchange h). Exchange layout hx[parity][g][c][4w]:
// b128 reads and uint2 writes are <=2-way bank aliased (free). Wave W owns
// units W*16..W*16+15: 4 MFMA blocks + 28 trans/step (half of v3's VALU),
// 2048 waves = 2/SIMD hides the dependency stalls.
__global__ __launch_bounds__(128, 2)
void vae_mfma6b_kernel(const float* __restrict__ x,      const float* __restrict__ eps,
                       const float* __restrict__ eWih,   const float* __restrict__ eWhh,
                       const float* __restrict__ ebih,   const float* __restrict__ ebhh,
                       const float* __restrict__ Wmu,    const float* __restrict__ bmu,
                       const float* __restrict__ Wlv,    const float* __restrict__ blv,
                       const float* __restrict__ Wl2h,   const float* __restrict__ bl2h,
                       const float* __restrict__ Wl2h2,  const float* __restrict__ bl2h2,
                       const float* __restrict__ stok,   const float* __restrict__ Wemb,
                       const float* __restrict__ bemb,
                       const float* __restrict__ dWih,   const float* __restrict__ dWhh,
                       const float* __restrict__ dbih,   const float* __restrict__ dbhh,
                       const float* __restrict__ Wout,   const float* __restrict__ bout,
                       const float* __restrict__ Wseq,   const float* __restrict__ bseq,
                       const float* __restrict__ Wseq2,  const float* __restrict__ bseq2,
                       float* __restrict__ recon,
                       float* __restrict__ out_mu,
                       float* __restrict__ out_lv,
                       float* __restrict__ out_num)
{
    __shared__ unsigned hx[2][4][16][4];  // [parity][word-group][batch col][word]
    __shared__ float hbf[16][33];
    __shared__ float cbf[16][33];
    __shared__ float mubuf[16];
    __shared__ float x0buf[32];
    __shared__ float cw[524];
    // cw: 0 Wmu[64] | 64 Wlv[64] | 128 Wseq[32] | 160 bseq[32] | 192 Wseq2[32]
    //     224 Wl2h[32] | 256 bl2h[32] | 288 Wl2h2[32] | 320 bl2h2[32]
    //     352 Wout[160] | 512 bout[5] | 517 bmu | 518 blv | 519 bseq2

    const int tid = threadIdx.x;
    const int W   = tid >> 6;   // unit half owned by this wave (units W*16..+15)
    const int l   = tid & 63;
    const int c   = l & 15;     // batch col / A-frag row
    const int g   = l >> 4;     // k-chunk / D row-group
    const int bbase = blockIdx.x * 16;

    if (tid < 64){ cw[tid] = Wmu[tid]; cw[64+tid] = Wlv[tid]; }
    if (tid >= 64 && tid < 96){
        const int i = tid - 64;
        cw[128+i] = Wseq[i];  cw[160+i] = bseq[i];  cw[192+i] = Wseq2[i];
        cw[224+i] = Wl2h[i];  cw[256+i] = bl2h[i];
        cw[288+i] = Wl2h2[i]; cw[320+i] = bl2h2[i];
    }
    if (tid < 128){ cw[352+tid] = Wout[tid]; }
    if (tid >= 96 && tid < 128){ int i = tid - 96; cw[480+i] = Wout[128+i]; }
    if (tid < 5)   cw[512+tid] = bout[tid];
    if (tid == 0){ cw[517] = bmu[0]; cw[518] = blv[0]; cw[519] = bseq2[0]; }

    // ---- encoder fragments: wave W covers gate rows n*32 + W*16 + r ----
    bf16x8 WH[4], WX[4];
    f32x4  biasv[4];
    #pragma unroll
    for (int n=0;n<4;++n){
        const float sc = (n==2) ? (-2.0f*LOG2E) : (-LOG2E);
        const int GR = n*32 + W*16 + c;
        bf16x8 t;
        #pragma unroll
        for (int j=0;j<8;++j) t[j] = (short)f2bf(sc * eWhh[(size_t)GR*32 + g*8 + j]);
        WH[n] = t;
        bf16x8 tx = (bf16x8)0;
        if (g == 0){
            #pragma unroll
            for (int j=0;j<5;++j) tx[j] = (short)f2bf(sc * eWih[(size_t)GR*5 + j]);
        }
        WX[n] = tx;
        f32x4 b4;
        #pragma unroll
        for (int q=0;q<4;++q){
            const int R = n*32 + W*16 + g*4 + q;
            b4[q] = sc * (ebih[R] + ebhh[R]);
        }
        biasv[n] = b4;
    }

    float cs[4], hn[4];
    #pragma unroll
    for (int k=0;k<4;++k){ cs[k] = 0.0f; hn[k] = 0.0f; }

    // prefill h(0)=0 into parity-0 buffer: lane (c,g) owns words W*8+g*2, +1
    *(uint2*)&hx[0][W*2 + (g>>1)][c][(g&1)*2] = make_uint2(0u, 0u);
    int p = 0;
    __syncthreads();     // also covers cw

    float4 xA = {0,0,0,0}; float xB = 0.0f;
    if (g == 0){
        const float* xp = x + (size_t)(bbase+c)*500;
        xA = *(const float4*)xp; xB = xp[4];
    }

    // ================= encoder LSTM (T=100) =================
    for (int t=0; t<100; ++t){
        u32x4 hw = *(const u32x4*)&hx[p][g][c][0];   // h words g*4..g*4+3
        bf16x8 bh = __builtin_bit_cast(bf16x8, hw);

        bf16x8 bx = (bf16x8)0;
        if (g == 0){
            bx[0]=(short)f2bf(xA.x); bx[1]=(short)f2bf(xA.y);
            bx[2]=(short)f2bf(xA.z); bx[3]=(short)f2bf(xA.w);
            bx[4]=(short)f2bf(xB);
            if (t < 99){
                const float* xp = x + (size_t)(bbase+c)*500 + (t+1)*5;
                xA = *(const float4*)xp; xB = xp[4];
            }
        }

        f32x4 acc[4];
        #pragma unroll
        for (int n=0;n<4;++n) acc[n] = mfma16(WX[n], bx, biasv[n]);   // independent of h-read
        #pragma unroll
        for (int n=0;n<4;++n) acc[n] = mfma16(WH[n], bh, acc[n]);

        #pragma unroll
        for (int q=0;q<4;++q){
            float ei = ex2(acc[0][q]);      // e^{-i}
            float ef = ex2(acc[1][q]);      // e^{-f}
            float eg = ex2(acc[2][q]);      // e^{-2g}
            float eo = ex2(acc[3][q]);      // e^{-o}
            float pig = (1.0f+ei)*(1.0f+eg);
            float num = cs[q]*pig + (1.0f+ef)*(1.0f-eg);
            float cn  = num * rcp_((1.0f+ef)*pig);
            float ec  = ex2(cn * (-2.0f*LOG2E));
            hn[q]     = (1.0f-ec) * rcp_((1.0f+eo)*(1.0f+ec));
            cs[q]     = cn;
        }
        *(uint2*)&hx[p^1][W*2 + (g>>1)][c][(g&1)*2] =
            make_uint2(pk_bf16(hn[0], hn[1]), pk_bf16(hn[2], hn[3]));
        __syncthreads();
        p ^= 1;
    }

    // ---- stage h_n / c_n (own 4 units) for heads ----
    #pragma unroll
    for (int q=0;q<4;++q){
        const int U = W*16 + g*4 + q;
        hbf[c][U] = hn[q];
        cbf[c][U] = cs[q];
    }
    __syncthreads();

    // ---- decoder fragments ----
    bf16x8 WI[4], WHd[4];
    f32x4  dbias[4];
    #pragma unroll
    for (int n=0;n<4;++n){
        const float sc = (n==2) ? (-2.0f*LOG2E) : (-LOG2E);
        const int GR = n*32 + W*16 + c;
        bf16x8 ti, th;
        #pragma unroll
        for (int j=0;j<8;++j){
            ti[j] = (short)f2bf(sc * dWih[(size_t)GR*32 + g*8 + j]);
            th[j] = (short)f2bf(sc * dWhh[(size_t)GR*32 + g*8 + j]);
        }
        WI[n] = ti; WHd[n] = th;
        f32x4 b4;
        #pragma unroll
        for (int q=0;q<4;++q){
            const int R = n*32 + W*16 + g*4 + q;
            b4[q] = sc * (dbih[R] + dbhh[R]);
        }
        dbias[n] = b4;
    }
    bf16x8 WO = (bf16x8)0;
    f32x4 bosv = (f32x4)0;
    if (c < 5){
        bf16x8 to;
        #pragma unroll
        for (int j=0;j<8;++j) to[j] = (short)f2bf(Wout[c*32 + g*8 + j]);
        WO = to;
    }
    #pragma unroll
    for (int q=0;q<4;++q){
        const int dd = g*4 + q;
        bosv[q] = (dd < 5) ? bout[dd] : 0.0f;
    }

    // ---- heads: 16 batch rows per block, one thread each ----
    if (tid < 16){
        const int row = bbase + tid;
        float mu = cw[517], lv = cw[518];
        #pragma unroll
        for (int k=0;k<32;++k){
            float hvv = hbf[tid][k], cvv = cbf[tid][k];
            mu += hvv*cw[k]    + cvv*cw[32+k];
            lv += hvv*cw[64+k] + cvv*cw[96+k];
        }
        out_mu[row] = mu;
        out_lv[row] = lv;
        mubuf[tid] = mu;
        float z = mu + eps[row] * __builtin_amdgcn_exp2f(0.5f*LOG2E*lv);
        float a2 = cw[519];
        #pragma unroll
        for (int j=0;j<32;++j){
            float s = z*cw[128+j] + cw[160+j];
            s = s > 0.0f ? s : 0.01f*s;
            a2 += cw[192+j]*s;
        }
        out_num[row] = fmaxf(a2, 0.0f);
    }
    if (tid >= 32 && tid < 64){
        const int u = tid - 32;
        float v = bemb[u];
        #pragma unroll
        for (int d=0; d<5; ++d) v += stok[d]*Wemb[u*5 + d];
        x0buf[u] = fmaxf(v, 0.0f);
    }
    __syncthreads();

    // ---- decoder init: own c0; own 4 h0 units packed into the exchange buf ----
    {
        const float muv = mubuf[c];
        float h4[4];
        #pragma unroll
        for (int q=0;q<4;++q){
            const int U = W*16 + g*4 + q;
            float a = muv*cw[224+U] + cw[256+U];
            float b = muv*cw[288+U] + cw[320+U];
            h4[q]  = (a > 0.0f ? a : 0.01f*a);
            cs[q]  = (b > 0.0f ? b : 0.01f*b);
        }
        *(uint2*)&hx[0][W*2 + (g>>1)][c][(g&1)*2] =
            make_uint2(pk_bf16(h4[0], h4[1]), pk_bf16(h4[2], h4[3]));
    }
    p = 0;
    __syncthreads();

    bf16x8 bx0;
    #pragma unroll
    for (int j=0;j<8;++j) bx0[j] = (short)f2bf(x0buf[g*8 + j]);

    // ================= decoder LSTM (T=100, autoregressive) =================
    for (int t=0; t<100; ++t){
        u32x4 hw = *(const u32x4*)&hx[p][g][c][0];
        bf16x8 bh = __builtin_bit_cast(bf16x8, hw);

        bf16x8 bx;
        if (t == 0) bx = bx0;
        else {
            u32x4 rv;
            #pragma unroll
            for (int i=0;i<4;++i) rv[i] = relu_pk(hw[i]);
            bx = __builtin_bit_cast(bf16x8, rv);
        }

        f32x4 acc[4];
        #pragma unroll
        for (int n=0;n<4;++n) acc[n] = mfma16(WI[n], bx, dbias[n]);
        #pragma unroll
        for (int n=0;n<4;++n) acc[n] = mfma16(WHd[n], bh, acc[n]);

        if (W == 0 && t > 0){    // recon row t-1 = Wout @ h_t (wave 0 only)
            f32x4 ao = mfma16(WO, bh, bosv);
            float* rp = recon + (size_t)(bbase+c)*500 + (t-1)*5;
            if (g == 0){ rp[0]=ao[0]; rp[1]=ao[1]; rp[2]=ao[2]; rp[3]=ao[3]; }
            else if (g == 1){ rp[4]=ao[0]; }
        }

        #pragma unroll
        for (int q=0;q<4;++q){
            float ei = ex2(acc[0][q]);
            float ef = ex2(acc[1][q]);
            float eg = ex2(acc[2][q]);
            float eo = ex2(acc[3][q]);
            float pig = (1.0f+ei)*(1.0f+eg);
            float num = cs[q]*pig + (1.0f+ef)*(1.0f-eg);
            float cn  = num * rcp_((1.0f+ef)*pig);
            float ec  = ex2(cn * (-2.0f*LOG2E));
            hn[q]     = (1.0f-ec) * rcp_((1.0f+eo)*(1.0f+ec));
            cs[q]     = cn;
        }
        *(uint2*)&hx[p^1][W*2 + (g>>1)][c][(g&1)*2] =
            make_uint2(pk_bf16(hn[0], hn[1]), pk_bf16(hn[2], hn[3]));
        __syncthreads();
        p ^= 1;
    }

    // final recon row 99 from h_100
    if (W == 0){
        u32x4 hw = *(const u32x4*)&hx[p][g][c][0];
        f32x4 ao = mfma16(WO, __builtin_bit_cast(bf16x8, hw), bosv);
        float* rp = recon + (size_t)(bbase+c)*500 + 99*5;
        if (g == 0){ rp[0]=ao[0]; rp[1]=ao[1]; rp[2]=ao[2]; rp[3]=ao[3]; }
        else if (g == 1){ rp[4]=ao[0]; }
    }
}

extern "C" void kernel_launch(void* const* d_in, const int* in_sizes, int n_in,
                              void* d_out, int out_size, void* d_ws, size_t ws_size,
                              hipStream_t stream)
{
    (void)d_ws; (void)ws_size;
    static const int EXPECT[27] = {8192000,16384,640,4096,128,128,64,1,64,1,
                                   32,32,32,32,5,160,32,4096,4096,128,128,
                                   160,5,32,32,32,1};
    bool in_ok = (n_in == 27);
    if (in_ok) for (int i = 0; i < 27; ++i) in_ok = in_ok && (in_sizes[i] == EXPECT[i]);
    bool out_ok = (out_size == 8241152);

    float* out = (float*)d_out;
    if (!in_ok){
        marker_kernel<<<(out_size + 255)/256, 256, 0, stream>>>(out, out_size, 2.0f);
        return;
    }
    if (!out_ok){
        marker_kernel<<<(out_size + 255)/256, 256, 0, stream>>>(out, out_size, 3.0f);
        return;
    }

    const float* x     = (const float*)d_in[0];
    const float* eps   = (const float*)d_in[1];
    const float* eWih  = (const float*)d_in[2];
    const float* eWhh  = (const float*)d_in[3];
    const float* ebih  = (const float*)d_in[4];
    const float* ebhh  = (const float*)d_in[5];
    const float* Wmu   = (const float*)d_in[6];
    const float* bmu   = (const float*)d_in[7];
    const float* Wlv   = (const float*)d_in[8];
    const float* blv   = (const float*)d_in[9];
    const float* Wl2h  = (const float*)d_in[10];
    const float* bl2h  = (const float*)d_in[11];
    const float* Wl2h2 = (const float*)d_in[12];
    const float* bl2h2 = (const float*)d_in[13];
    const float* stok  = (const float*)d_in[14];
    const float* Wemb  = (const float*)d_in[15];
    const float* bemb  = (const float*)d_in[16];
    const float* dWih  = (const float*)d_in[17];
    const float* dWhh  = (const float*)d_in[18];
    const float* dbih  = (const float*)d_in[19];
    const float* dbhh  = (const float*)d_in[20];
    const float* Wout  = (const float*)d_in[21];
    const float* bout  = (const float*)d_in[22];
    const float* Wseq  = (const float*)d_in[23];
    const float* bseq  = (const float*)d_in[24];
    const float* Wseq2 = (const float*)d_in[25];
    const float* bseq2 = (const float*)d_in[26];

    float* recon  = out;                 // [16384][100][5] f32
    float* out_mu = out + 8192000;       // [16384]
    float* out_lv = out_mu + 16384;      // [16384]
    float* out_nm = out_lv + 16384;      // [16384]

    vae_mfma6b_kernel<<<1024, 128, 0, stream>>>(x, eps,
        eWih, eWhh, ebih, ebhh, Wmu, bmu, Wlv, blv,
        Wl2h, bl2h, Wl2h2, bl2h2, stok, Wemb, bemb,
        dWih, dWhh, dbih, dbhh, Wout, bout,
        Wseq, bseq, Wseq2, bseq2,
        recon, out_mu, out_lv, out_nm);
}